// Round 13
// baseline (518.968 us; speedup 1.0000x reference)
//
#include <hip/hip_runtime.h>

// Aggregator: scores = mean(ue*nr, dim); softmax over 32 neighbors;
// out = relu(mean(w * nv, neighbors)).  B=4096, NITER=8, NSIZE=32, DIM=64.
//
// Persistent-wave streaming version: each wave processes NT=4 tasks with a
// 2-deep register double-buffer (loads for task t+1 issued before compute
// of task t -> ~17-34 KB continuously in flight per wave, copy-ubench
// style). All global loads are contiguous wave-wide dwordx4 (1 KB/instr):
// lane l, step j reads float4 #(j*64+l) of the task tile; that element is
// neighbor s = j*4 + (l>>4), dim-quad q = l&15.

constexpr int DIM = 64;
constexpr int NSIZE = 32;
constexpr int NT = 4;     // tasks per wave
constexpr int WPB = 4;    // waves per 256-thread block

__device__ __forceinline__ void load_task(
    const float4* __restrict__ nr4, const float4* __restrict__ nv4,
    const float* __restrict__ ue, int t, int niter, int lane, int q,
    float4 (&a)[8], float4 (&v)[8], float4& u) {
  const float4* A = nr4 + (size_t)t * 512;   // 512 float4 per 32x64 tile
  const float4* V = nv4 + (size_t)t * 512;
#pragma unroll
  for (int j = 0; j < 8; ++j) a[j] = A[j * 64 + lane];
#pragma unroll
  for (int j = 0; j < 8; ++j) v[j] = V[j * 64 + lane];
  int b = t / niter;
  u = ((const float4*)(ue + (size_t)b * DIM))[q];
}

__device__ __forceinline__ void compute_task(
    const float4 (&a)[8], const float4 (&v)[8], const float4& u,
    float* __restrict__ out, int t, int lane, int q) {
  // scores: partial dot over dims 4q..4q+3, reduce across 16-lane group.
  float sc[8];
#pragma unroll
  for (int j = 0; j < 8; ++j) {
    float p = a[j].x * u.x;
    p = fmaf(a[j].y, u.y, p);
    p = fmaf(a[j].z, u.z, p);
    p = fmaf(a[j].w, u.w, p);
#pragma unroll
    for (int k = 1; k < 16; k <<= 1) p += __shfl_xor(p, k);
    sc[j] = p * (1.0f / DIM);
  }
  // softmax over 32 neighbors (8 local + cross-group 16,32)
  float m = sc[0];
#pragma unroll
  for (int j = 1; j < 8; ++j) m = fmaxf(m, sc[j]);
  m = fmaxf(m, __shfl_xor(m, 16));
  m = fmaxf(m, __shfl_xor(m, 32));
  float e[8];
  float z = 0.f;
#pragma unroll
  for (int j = 0; j < 8; ++j) {
    e[j] = __expf(sc[j] - m);
    z += e[j];
  }
  z += __shfl_xor(z, 16);
  z += __shfl_xor(z, 32);
  float inv = 1.0f / (z * (float)NSIZE);  // fold 1/NSIZE neighbor-mean in

  float4 acc = make_float4(0.f, 0.f, 0.f, 0.f);
#pragma unroll
  for (int j = 0; j < 8; ++j) {
    float w = e[j] * inv;
    acc.x = fmaf(w, v[j].x, acc.x);
    acc.y = fmaf(w, v[j].y, acc.y);
    acc.z = fmaf(w, v[j].z, acc.z);
    acc.w = fmaf(w, v[j].w, acc.w);
  }
#pragma unroll
  for (int k = 16; k < 64; k <<= 1) {
    acc.x += __shfl_xor(acc.x, k);
    acc.y += __shfl_xor(acc.y, k);
    acc.z += __shfl_xor(acc.z, k);
    acc.w += __shfl_xor(acc.w, k);
  }
  if (lane < 16) {
    float4 r = make_float4(fmaxf(acc.x, 0.f), fmaxf(acc.y, 0.f),
                           fmaxf(acc.z, 0.f), fmaxf(acc.w, 0.f));
    ((float4*)(out + (size_t)t * DIM))[q] = r;
  }
}

__global__ __launch_bounds__(256, 2) void Aggregator_kernel(
    const float* __restrict__ nv, const float* __restrict__ nr,
    const float* __restrict__ ue, float* __restrict__ out,
    int niter, int ntasks) {
  int wave = (int)(blockIdx.x * WPB + (threadIdx.x >> 6));
  int nwaves = (int)(gridDim.x * WPB);
  int lane = (int)(threadIdx.x & 63);
  int q = lane & 15;

  const float4* nr4 = (const float4*)nr;
  const float4* nv4 = (const float4*)nv;

  int t0 = wave;
  int t1 = wave + nwaves;
  int t2 = wave + 2 * nwaves;
  int t3 = wave + 3 * nwaves;

  float4 a0[8], v0[8], u0;
  float4 a1[8], v1[8], u1;

  // pipeline: loads(t+1) issued before compute(t); counted vmcnt keeps
  // the younger loads in flight across each compute.
  if (t0 < ntasks) load_task(nr4, nv4, ue, t0, niter, lane, q, a0, v0, u0);
  if (t1 < ntasks) load_task(nr4, nv4, ue, t1, niter, lane, q, a1, v1, u1);
  if (t0 < ntasks) compute_task(a0, v0, u0, out, t0, lane, q);
  if (t2 < ntasks) load_task(nr4, nv4, ue, t2, niter, lane, q, a0, v0, u0);
  if (t1 < ntasks) compute_task(a1, v1, u1, out, t1, lane, q);
  if (t3 < ntasks) load_task(nr4, nv4, ue, t3, niter, lane, q, a1, v1, u1);
  if (t2 < ntasks) compute_task(a0, v0, u0, out, t2, lane, q);
  if (t3 < ntasks) compute_task(a1, v1, u1, out, t3, lane, q);
}

extern "C" void kernel_launch(void* const* d_in, const int* in_sizes, int n_in,
                              void* d_out, int out_size, void* d_ws, size_t ws_size,
                              hipStream_t stream) {
  // inputs: 0=self_vectors (unused), 1=neighbor_vectors, 2=neighbor_relations,
  //         3=user_embeddings, 4=neighbor_size (derived instead)
  const float* nv = (const float*)d_in[1];
  const float* nr = (const float*)d_in[2];
  const float* ue = (const float*)d_in[3];
  float* out = (float*)d_out;

  int ntasks = in_sizes[0] / DIM;          // B * NITER = 32768
  int niter  = in_sizes[0] / in_sizes[3];  // NITER = 8
  int blocks = (ntasks + WPB * NT - 1) / (WPB * NT);  // 2048
  Aggregator_kernel<<<blocks, 256, 0, stream>>>(nv, nr, ue, out, niter, ntasks);
}